// Round 1
// baseline (56.002 us; speedup 1.0000x reference)
//
#include <hip/hip_runtime.h>

// QuantumLayer analytic solution.
//
// RZ layers are unit-modulus diagonal phases and the CNOT chain is a basis
// permutation, so q_weights cancels in |amplitude|^2. The RY product state
// gives independent wire-bits with E[z_i] = cos(x_i); after L prefix-xor
// permutations, output wire w is the XOR of a wire-set S_w, so
//   out[b,w] = prod_{m in S_w} cos(x[b,m])
// Masks S_w computed generically for runtime L (XOR prefix recurrence).
//
// This round: 2 rows per thread. A row is 40 B (not 16B-alignable), but a
// row-PAIR is 80 B = 5 x float4, 16-byte aligned -> dwordx4 loads/stores,
// half the VMEM instructions and waves, 5 independent 16B loads in flight
// per thread. Dispatch remains overhead/latency-bound; this minimizes the
// in-kernel critical path.

constexpr int N = 10;  // n wires (x is [B, 10] per reference setup)

__global__ __launch_bounds__(64) void qlayer_kernel(const float* __restrict__ x,
                                                    float* __restrict__ out,
                                                    int B, int L) {
    const int pair = blockIdx.x * 64 + threadIdx.x;
    const int row0 = pair * 2;
    if (row0 >= B) return;

    const bool full = (row0 + 1 < B);  // B odd -> last thread does 1 row

    // cos of the 20 inputs of the row pair (c[0..9] row0, c[10..19] row1).
    // |x| ~ N(0,1): __cosf (v_cos_f32) abs err ~1e-6 vs 2e-2 threshold.
    float c[2 * N];
    if (full) {
        const float4* x4 = (const float4*)(x + (size_t)row0 * N);
#pragma unroll
        for (int i = 0; i < 5; ++i) {
            float4 v = x4[i];
            c[4 * i + 0] = __cosf(v.x);
            c[4 * i + 1] = __cosf(v.y);
            c[4 * i + 2] = __cosf(v.z);
            c[4 * i + 3] = __cosf(v.w);
        }
    } else {
#pragma unroll
        for (int m = 0; m < N; ++m) c[m] = __cosf(x[(size_t)row0 * N + m]);
#pragma unroll
        for (int m = 0; m < N; ++m) c[N + m] = 1.0f;
    }

    // masks[w] = input wires whose bits XOR into output wire w after L layers.
    unsigned mask[N];
#pragma unroll
    for (int w = 0; w < N; ++w) mask[w] = 1u << w;
    for (int l = 0; l < L; ++l) {
        unsigned acc = 0;
#pragma unroll
        for (int w = 0; w < N; ++w) { acc ^= mask[w]; mask[w] = acc; }
    }

    // Predicated products; all indices compile-time (no scratch spills).
    float r[2 * N];
#pragma unroll
    for (int w = 0; w < N; ++w) {
        float p0 = 1.0f, p1 = 1.0f;
#pragma unroll
        for (int m = 0; m < N; ++m) {
            const bool on = (mask[w] >> m) & 1u;
            p0 *= on ? c[m] : 1.0f;
            p1 *= on ? c[N + m] : 1.0f;
        }
        r[w] = p0;
        r[N + w] = p1;
    }

    if (full) {
        float4* o4 = (float4*)(out + (size_t)row0 * N);
#pragma unroll
        for (int i = 0; i < 5; ++i)
            o4[i] = make_float4(r[4 * i + 0], r[4 * i + 1],
                                r[4 * i + 2], r[4 * i + 3]);
    } else {
#pragma unroll
        for (int m = 0; m < N; ++m) out[(size_t)row0 * N + m] = r[m];
    }
}

extern "C" void kernel_launch(void* const* d_in, const int* in_sizes, int n_in,
                              void* d_out, int out_size, void* d_ws, size_t ws_size,
                              hipStream_t stream) {
    const float* x = (const float*)d_in[0];
    // d_in[1] = q_weights: provably unused — RZ phases cancel in |amplitude|^2.
    const int B = in_sizes[0] / N;
    const int L = in_sizes[1] / N;  // number of layers (2 in reference setup)
    const int pairs = (B + 1) / 2;
    const int blocks = (pairs + 63) / 64;
    qlayer_kernel<<<blocks, 64, 0, stream>>>(x, (float*)d_out, B, L);
}